// Round 8
// baseline (78.102 us; speedup 1.0000x reference)
//
#include <hip/hip_runtime.h>
#include <math.h>

// Spectral NS projection step, 512x512 fp32 periodic — radix-8 register FFT.
//
// v8: v7 (3 kernels, coalesced stores, XCD-contiguous maps, p-recompute)
// + ILP-2: every wave owns TWO FFT lines; all kernels 256 blocks x 64 thr.
//  - twiddle tables computed once per 2 lines
//  - kB: mirror pair (c0, 512-c0) in ONE wave -> beta/su/u2x/log-exp chain
//    shared between the two columns (sin flips sign, sin^2 equal); mirror
//    spectrum = sibling chain's LDS stage; single-wave blocks (no barrier
//    cost)
//  - kA/kC: adjacent row pair (i0,i0+1): stencil halo shared; kC's
//    transposed gather is a float4 (both rows per 16B access)
//
//  kA (256x64): rows i0=(b&7)*64+2*(b>>3), i0+1; stencil + fwd row FFT x2;
//               Zt row-major coalesced.
//  kB (256x64): cols cA=(b&7)*32+(b>>3), cB=512-cA (cA==0 -> {0,256});
//               gather cols, fwd FFT x2, shared-multiplier, inv FFT x2,
//               W1 col-major coalesced.
//  kC (256x64): float4-gather rows (i0,i0+1) from W1, inv row FFT x2,
//               recompute p (stencil, halo shared), out = p - grad(phi).
//
// Multiplier (exact identity): M = r^1000 - (1-r^1000)/(4-s), r=s/4,
//   s=2cos ai+2cos aj;  4-s = 4(sin^2(ai/2)+sin^2(aj/2)) (cancellation-free)
//   W(k) = (beta/2)[(sx^2+sy^2) Z(k) + (sx+i sy)^2 conj(Z(-k))], beta=-10M/512^2
// sin/cos over k stepped by pi/8 Givens rotation (1 sincosf per thread).
//
// Stockham radix-8, 3 stages, reads always buf[t+64m] (conflict-free);
// LDS scatter writes padded by idx+(idx>>3) -> near-uniform bank usage.

#define HH 512
#define WW 512
#define NCELL (HH * WW)
#define NU_C 0.1f
#define PI_F 3.14159265358979323846f
#define PADDED 576   // pad(511)=574

__device__ __forceinline__ int padi(int i) { return i + (i >> 3); }

__device__ __forceinline__ float2 cadd(float2 a, float2 b) { return make_float2(a.x + b.x, a.y + b.y); }
__device__ __forceinline__ float2 csub(float2 a, float2 b) { return make_float2(a.x - b.x, a.y - b.y); }
__device__ __forceinline__ float2 cmul(float2 a, float2 b) {
    return make_float2(a.x * b.x - a.y * b.y, a.x * b.y + a.y * b.x);
}

// twiddle tables are stored FORWARD (cis(-theta)); inverse conjugates on use
template <int S>
__device__ __forceinline__ float2 cmul_tw(float2 a, float2 w) {
    float wy = (S < 0) ? w.y : -w.y;
    return make_float2(a.x * w.x - a.y * wy, a.x * wy + a.y * w.x);
}

// 8-point DFT, S=-1 forward (e^{-2pi i km/8}), S=+1 inverse
template <int S>
__device__ __forceinline__ void bfly8(float2 r[8]) {
    const float c = 0.70710678118654752f;
    const float s = (float)S;
    float2 e0 = cadd(r[0], r[4]), f0 = csub(r[0], r[4]);
    float2 e1 = cadd(r[2], r[6]), f1 = csub(r[2], r[6]);
    float2 g0 = cadd(r[1], r[5]), h0 = csub(r[1], r[5]);
    float2 g1 = cadd(r[3], r[7]), h1 = csub(r[3], r[7]);
    float2 E0 = cadd(e0, e1), E2 = csub(e0, e1);
    float2 if1 = make_float2(-s * f1.y, s * f1.x);       // s*i*f1
    float2 E1 = cadd(f0, if1), E3 = csub(f0, if1);
    float2 O0 = cadd(g0, g1), O2 = csub(g0, g1);
    float2 ih1 = make_float2(-s * h1.y, s * h1.x);
    float2 O1 = cadd(h0, ih1), O3 = csub(h0, ih1);
    float2 t1 = make_float2(c * (O1.x - s * O1.y), c * (O1.y + s * O1.x)); // W8^s1 * O1
    float2 t2 = make_float2(-s * O2.y, s * O2.x);                          // s*i*O2
    float2 t3 = make_float2(-c * (O3.x + s * O3.y), -c * (O3.y - s * O3.x));
    r[0] = cadd(E0, O0); r[4] = csub(E0, O0);
    r[1] = cadd(E1, t1); r[5] = csub(E1, t1);
    r[2] = cadd(E2, t2); r[6] = csub(E2, t2);
    r[3] = cadd(E3, t3); r[7] = csub(E3, t3);
}

struct Twid { float2 s1[8]; float2 s2[8]; };

__device__ __forceinline__ void make_tw(Twid& tw, int t) {
    float sn, cs;
    sincosf(-2.0f * PI_F * (float)(t & 7) * (1.0f / 64.0f), &sn, &cs);
    float2 T1 = make_float2(cs, sn);
    tw.s1[0] = make_float2(1.0f, 0.0f);
#pragma unroll
    for (int m = 1; m < 8; ++m) tw.s1[m] = cmul(tw.s1[m - 1], T1);
    sincosf(-2.0f * PI_F * (float)t * (1.0f / 512.0f), &sn, &cs);
    float2 T2 = make_float2(cs, sn);
    tw.s2[0] = make_float2(1.0f, 0.0f);
#pragma unroll
    for (int m = 1; m < 8; ++m) tw.s2[m] = cmul(tw.s2[m - 1], T2);
}

// two interleaved 512-pt Stockham radix-8 FFTs (ILP-2, shared twiddles)
template <int S>
__device__ __forceinline__ void fft512x2(float2 ra[8], float2 rb[8], const Twid& tw,
                                         float2* a0, float2* a1,
                                         float2* b0, float2* b1, int t) {
    bfly8<S>(ra); bfly8<S>(rb);
#pragma unroll
    for (int k = 0; k < 8; ++k) { a0[padi(8 * t + k)] = ra[k]; b0[padi(8 * t + k)] = rb[k]; }
    __syncthreads();
#pragma unroll
    for (int m = 0; m < 8; ++m) { ra[m] = a0[padi(t + 64 * m)]; rb[m] = b0[padi(t + 64 * m)]; }
#pragma unroll
    for (int m = 1; m < 8; ++m) { ra[m] = cmul_tw<S>(ra[m], tw.s1[m]); rb[m] = cmul_tw<S>(rb[m], tw.s1[m]); }
    bfly8<S>(ra); bfly8<S>(rb);
    int base = ((t >> 3) << 6) + (t & 7);
#pragma unroll
    for (int k = 0; k < 8; ++k) { a1[padi(base + 8 * k)] = ra[k]; b1[padi(base + 8 * k)] = rb[k]; }
    __syncthreads();
#pragma unroll
    for (int m = 0; m < 8; ++m) { ra[m] = a1[padi(t + 64 * m)]; rb[m] = b1[padi(t + 64 * m)]; }
#pragma unroll
    for (int m = 1; m < 8; ++m) { ra[m] = cmul_tw<S>(ra[m], tw.s2[m]); rb[m] = cmul_tw<S>(rb[m], tw.s2[m]); }
    bfly8<S>(ra); bfly8<S>(rb);
}

// stencil for adjacent row pair (i0, i0+1), halo rows shared
__device__ __forceinline__ void stencil_rows2(const float* __restrict__ X,
                                              const float* __restrict__ F,
                                              int i0, int t,
                                              float pA0[8], float pA1[8],
                                              float pB0[8], float pB1[8]) {
    const int i1 = i0 + 1;
    const int iu = (i0 + 511) & 511, id = (i1 + 1) & 511;
    const float* X0 = X;
    const float* X1 = X + NCELL;
#pragma unroll
    for (int m = 0; m < 8; ++m) {
        int j = t + 64 * m;
        int jp = (j + 1) & 511, jm = (j + 511) & 511;
        float a_u = X0[iu * WW + j], a_0 = X0[i0 * WW + j];
        float a_1 = X0[i1 * WW + j], a_d = X0[id * WW + j];
        float a0p = X0[i0 * WW + jp], a0m = X0[i0 * WW + jm];
        float a1p = X0[i1 * WW + jp], a1m = X0[i1 * WW + jm];
        float b_u = X1[iu * WW + j], b_0 = X1[i0 * WW + j];
        float b_1 = X1[i1 * WW + j], b_d = X1[id * WW + j];
        float b0p = X1[i0 * WW + jp], b0m = X1[i0 * WW + jm];
        float b1p = X1[i1 * WW + jp], b1m = X1[i1 * WW + jm];
        // row i0 (ip -> a_1/b_1, im -> a_u/b_u)
        pA0[m] = -(a_0 * (a_1 - a_u) * 0.5f + b_0 * (a0p - a0m) * 0.5f)
               + NU_C * (a_1 + a_u + a0p + a0m - 4.0f * a_0) + F[i0 * WW + j];
        pA1[m] = -(a_0 * (b_1 - b_u) * 0.5f + b_0 * (b0p - b0m) * 0.5f)
               + NU_C * (b_1 + b_u + b0p + b0m - 4.0f * b_0) + F[NCELL + i0 * WW + j];
        // row i1 (ip -> a_d/b_d, im -> a_0/b_0)
        pB0[m] = -(a_1 * (a_d - a_0) * 0.5f + b_1 * (a1p - a1m) * 0.5f)
               + NU_C * (a_d + a_0 + a1p + a1m - 4.0f * a_1) + F[i1 * WW + j];
        pB1[m] = -(a_1 * (b_d - b_0) * 0.5f + b_1 * (b1p - b1m) * 0.5f)
               + NU_C * (b_d + b_0 + b1p + b1m - 4.0f * b_1) + F[NCELL + i1 * WW + j];
    }
}

__device__ __forceinline__ float beta_of(float qs) {
    float rN;              // r^1000 = |r|^1000, r = 1-qs
    if (qs < 1.0f)      rN = expf(1000.0f * log1pf(-qs));
    else if (qs > 1.0f) rN = expf(1000.0f * logf(qs - 1.0f));
    else                rN = 0.0f;
    float M = rN - (1.0f - rN) / (4.0f * qs);
    return -10.0f * M * (1.0f / (512.0f * 512.0f));
}

// --------------------------------------------- phase A: stencil + row FFT x2
__global__ __launch_bounds__(64) void kA(const float* __restrict__ X,
                                         const float* __restrict__ F,
                                         float2* __restrict__ Zt) {
    __shared__ float2 bA0[PADDED], bA1[PADDED], bB0[PADDED], bB1[PADDED];
    const int b = blockIdx.x, t = threadIdx.x;
    const int i0 = (b & 7) * 64 + 2 * (b >> 3);   // XCD x owns rows [64x,64x+64)
    Twid tw; make_tw(tw, t);
    float pA0[8], pA1[8], pB0[8], pB1[8];
    stencil_rows2(X, F, i0, t, pA0, pA1, pB0, pB1);
    float2 ra[8], rb[8];
#pragma unroll
    for (int m = 0; m < 8; ++m) { ra[m] = make_float2(pA0[m], pA1[m]); rb[m] = make_float2(pB0[m], pB1[m]); }
    fft512x2<-1>(ra, rb, tw, bA0, bA1, bB0, bB1, t);
    // ROW-major coalesced spectrum stores (transpose deferred to kB's gather)
#pragma unroll
    for (int k = 0; k < 8; ++k) {
        Zt[i0 * 512 + t + 64 * k]       = ra[k];
        Zt[(i0 + 1) * 512 + t + 64 * k] = rb[k];
    }
}

// ------- phase B: mirror-pair col FFT + shared multiplier + inverse, ILP-2
__global__ __launch_bounds__(64) void kB(const float2* __restrict__ Zt,
                                         float2* __restrict__ W1) {
    __shared__ float2 bA0[PADDED], bA1[PADDED], bB0[PADDED], bB1[PADDED];
    const int b = blockIdx.x, t = threadIdx.x;
    const int c0 = (b & 7) * 32 + (b >> 3);       // 0..255 distinct, XCD-contiguous
    const int cA = c0;
    const int cB = (c0 == 0) ? 256 : 512 - c0;
    Twid tw; make_tw(tw, t);
    float2 ra[8], rb[8];
    // gather both columns (16 outstanding stride-4KB loads, XCD-local lines)
#pragma unroll
    for (int m = 0; m < 8; ++m) {
        ra[m] = Zt[(t + 64 * m) * 512 + cA];
        rb[m] = Zt[(t + 64 * m) * 512 + cB];
    }
    fft512x2<-1>(ra, rb, tw, bA0, bA1, bB0, bB1, t);
    // stage spectra linearly for mirror access
#pragma unroll
    for (int k = 0; k < 8; ++k) { bA0[t + 64 * k] = ra[k]; bB0[t + 64 * k] = rb[k]; }
    __syncthreads();
    // mirror sources: col 512-cA = cB (stage B), col 512-cB = cA (stage A);
    // c0==0: both cols self-mirror
    const float2* mA = (c0 == 0) ? bA0 : bB0;
    const float2* mB = (c0 == 0) ? bB0 : bA0;

    // shared angular terms: syB = -syA, qyB = qyA  (c0>=1); c0==0 special
    float syA, qyA, syB, qyB;
    if (c0 == 0) { syA = 0.0f; qyA = 0.0f; syB = 0.0f; qyB = 1.0f; }
    else {
        float shy, chy;
        sincosf(PI_F * (float)c0 * (1.0f / 512.0f), &shy, &chy);
        syA = 2.0f * shy * chy; qyA = shy * shy;
        syB = -syA; qyB = qyA;
    }
    // sin/cos(pi*ki/512) stepped by pi/8 per k (exact-constant Givens rotation)
    float sh, ch;
    sincosf(PI_F * (float)t * (1.0f / 512.0f), &sh, &ch);
    const float c8 = 0.92387953251128675613f;  // cos(pi/8)
    const float s8 = 0.38268343236508977173f;  // sin(pi/8)
#pragma unroll
    for (int k = 0; k < 8; ++k) {
        int ki = t + 64 * k;
        int mi = (HH - ki) & 511;
        float sx = 2.0f * sh * ch;
        float qx = sh * sh;
        // beta shared between the pair (qyB==qyA) except the c0==0 block
        float betaA = (ki == 0 && c0 == 0) ? 0.0f : beta_of(qx + qyA);
        float betaB;
        if (c0 == 0) betaB = beta_of(qx + qyB);
        else         betaB = betaA;
        float sy2 = syA * syA;                 // == syB*syB
        float su  = sx * sx + sy2;
        float u2x = sx * sx - sy2;
        float u2yA = 2.0f * sx * syA;
        float u2yB = -u2yA;                    // 2*sx*syB
        // chain A
        {
            float2 z = ra[k], zc = mA[mi];
            float cx = zc.x, cy = -zc.y;       // conj(Z(-k))
            float tx = u2x * cx - u2yA * cy;
            float ty = u2x * cy + u2yA * cx;
            float bh = 0.5f * betaA;
            ra[k] = make_float2(bh * (su * z.x + tx), bh * (su * z.y + ty));
        }
        // chain B
        {
            float2 z = rb[k], zc = mB[mi];
            float cx = zc.x, cy = -zc.y;
            float tx = u2x * cx - u2yB * cy;
            float ty = u2x * cy + u2yB * cx;
            float bh = 0.5f * betaB;
            rb[k] = make_float2(bh * (su * z.x + tx), bh * (su * z.y + ty));
        }
        float nch = ch * c8 - sh * s8;         // advance angle by pi/8
        sh = sh * c8 + ch * s8;
        ch = nch;
    }
    __syncthreads();   // all mirror reads done before inverse FFT clobbers LDS
    fft512x2<1>(ra, rb, tw, bA0, bA1, bB0, bB1, t);
    // COLUMN-major coalesced stores (transpose deferred to kC's gather)
#pragma unroll
    for (int k = 0; k < 8; ++k) {
        W1[cA * 512 + t + 64 * k] = ra[k];
        W1[cB * 512 + t + 64 * k] = rb[k];
    }
}

// --------------------------------------- phase C: inverse row FFT x2 + output
__global__ __launch_bounds__(64) void kC(const float2* __restrict__ W1,
                                         const float* __restrict__ X,
                                         const float* __restrict__ F,
                                         float* __restrict__ out) {
    __shared__ float2 bA0[PADDED], bA1[PADDED], bB0[PADDED], bB1[PADDED];
    const int b = blockIdx.x, t = threadIdx.x;
    const int i0 = (b & 7) * 64 + 2 * (b >> 3);   // even; XCD-contiguous rows
    Twid tw; make_tw(tw, t);
    float2 ra[8], rb[8];
    // float4 gather: both rows' values per 16B access (i0 even -> aligned)
#pragma unroll
    for (int m = 0; m < 8; ++m) {
        float4 v = *reinterpret_cast<const float4*>(&W1[(t + 64 * m) * 512 + i0]);
        ra[m] = make_float2(v.x, v.y);
        rb[m] = make_float2(v.z, v.w);
    }
    // stencil recompute (bitwise-identical to kA's p) hides under the gather
    float pA0[8], pA1[8], pB0[8], pB1[8];
    stencil_rows2(X, F, i0, t, pA0, pA1, pB0, pB1);
    fft512x2<1>(ra, rb, tw, bA0, bA1, bB0, bB1, t);
#pragma unroll
    for (int k = 0; k < 8; ++k) {
        int j = t + 64 * k;
        out[i0 * WW + j]               = pA0[k] - ra[k].x;
        out[NCELL + i0 * WW + j]       = pA1[k] - ra[k].y;
        out[(i0 + 1) * WW + j]         = pB0[k] - rb[k].x;
        out[NCELL + (i0 + 1) * WW + j] = pB1[k] - rb[k].y;
    }
}

// ---------------------------------------------------------------------------
extern "C" void kernel_launch(void* const* d_in, const int* in_sizes, int n_in,
                              void* d_out, int out_size, void* d_ws, size_t ws_size,
                              hipStream_t stream) {
    const float* X = (const float*)d_in[1];
    const float* F = (const float*)d_in[2];
    float* out = (float*)d_out;
    float* ws  = (float*)d_ws;

    float2* Zt = (float2*)ws;                 // NCELL float2 (2 MB), row-major
    float2* W1 = Zt + NCELL;                  // NCELL float2 (2 MB), col-major

    kA<<<dim3(256), dim3(64), 0, stream>>>(X, F, Zt);
    kB<<<dim3(256), dim3(64), 0, stream>>>(Zt, W1);
    kC<<<dim3(256), dim3(64), 0, stream>>>(W1, X, F, out);
}

// Round 9
// 73.357 us; speedup vs baseline: 1.0647x; 1.0647x over previous
//
#include <hip/hip_runtime.h>
#include <math.h>

// Spectral NS projection step, 512x512 fp32 periodic — radix-8 register FFT.
//
// v9: v7 structure (3 kernels, 512-wave spread, coalesced stores, XCD maps,
// p-recompute in kC) + critical-path surgery:
//  - kB: beta/log-exp chain + Givens angular terms precomputed BEFORE the
//    forward FFT, overlapped with the column-gather latency (previously this
//    ~1000cy transcendental chain sat serialized between fwd and inv FFT).
//  - kC: nontemporal stores for out (written once, never re-read on device).
//
//  kA (512x64) : row i=(b&7)*64+(b>>3); stencil + fwd row FFT; Zt row-major.
//  kB (256x128): base col c0=(b&7)*32+(b>>3); wave w: col {c0, 512-c0}
//                (c0==0 -> {0,256}, self-mirror); gather col from Zt, fwd
//                FFT, conj(Z(-k)) via intra-block LDS (mirror wave), exact
//                1000-step-Jacobi multiplier, inv FFT, W1 col-major.
//  kC (512x64) : row i=(b&7)*64+(b>>3); gather row from W1, inv row FFT,
//                recompute p, out = p - grad(phi).
//
// Multiplier (exact identity): M = r^1000 - (1-r^1000)/(4-s), r=s/4,
//   s=2cos ai+2cos aj;  4-s = 4(sin^2(ai/2)+sin^2(aj/2)) (cancellation-free)
//   W(k) = (beta/2)[(sx^2+sy^2) Z(k) + (sx+i sy)^2 conj(Z(-k))], beta=-10M/512^2
// sin/cos over k stepped by pi/8 Givens rotation (1 sincosf per thread).
//
// Stockham radix-8, 3 stages, reads always buf[t+64m] (conflict-free);
// LDS scatter writes padded by idx+(idx>>3) -> near-uniform bank usage.

#define HH 512
#define WW 512
#define NCELL (HH * WW)
#define NU_C 0.1f
#define PI_F 3.14159265358979323846f
#define PADDED 576   // pad(511)=574

__device__ __forceinline__ int padi(int i) { return i + (i >> 3); }

__device__ __forceinline__ float2 cadd(float2 a, float2 b) { return make_float2(a.x + b.x, a.y + b.y); }
__device__ __forceinline__ float2 csub(float2 a, float2 b) { return make_float2(a.x - b.x, a.y - b.y); }
__device__ __forceinline__ float2 cmul(float2 a, float2 b) {
    return make_float2(a.x * b.x - a.y * b.y, a.x * b.y + a.y * b.x);
}

// twiddle tables are stored FORWARD (cis(-theta)); inverse conjugates on use
template <int S>
__device__ __forceinline__ float2 cmul_tw(float2 a, float2 w) {
    float wy = (S < 0) ? w.y : -w.y;
    return make_float2(a.x * w.x - a.y * wy, a.x * wy + a.y * w.x);
}

// 8-point DFT, S=-1 forward (e^{-2pi i km/8}), S=+1 inverse
template <int S>
__device__ __forceinline__ void bfly8(float2 r[8]) {
    const float c = 0.70710678118654752f;
    const float s = (float)S;
    float2 e0 = cadd(r[0], r[4]), f0 = csub(r[0], r[4]);
    float2 e1 = cadd(r[2], r[6]), f1 = csub(r[2], r[6]);
    float2 g0 = cadd(r[1], r[5]), h0 = csub(r[1], r[5]);
    float2 g1 = cadd(r[3], r[7]), h1 = csub(r[3], r[7]);
    float2 E0 = cadd(e0, e1), E2 = csub(e0, e1);
    float2 if1 = make_float2(-s * f1.y, s * f1.x);       // s*i*f1
    float2 E1 = cadd(f0, if1), E3 = csub(f0, if1);
    float2 O0 = cadd(g0, g1), O2 = csub(g0, g1);
    float2 ih1 = make_float2(-s * h1.y, s * h1.x);
    float2 O1 = cadd(h0, ih1), O3 = csub(h0, ih1);
    float2 t1 = make_float2(c * (O1.x - s * O1.y), c * (O1.y + s * O1.x)); // W8^s1 * O1
    float2 t2 = make_float2(-s * O2.y, s * O2.x);                          // s*i*O2
    float2 t3 = make_float2(-c * (O3.x + s * O3.y), -c * (O3.y - s * O3.x));
    r[0] = cadd(E0, O0); r[4] = csub(E0, O0);
    r[1] = cadd(E1, t1); r[5] = csub(E1, t1);
    r[2] = cadd(E2, t2); r[6] = csub(E2, t2);
    r[3] = cadd(E3, t3); r[7] = csub(E3, t3);
}

struct Twid { float2 s1[8]; float2 s2[8]; };

__device__ __forceinline__ void make_tw(Twid& tw, int t) {
    float sn, cs;
    sincosf(-2.0f * PI_F * (float)(t & 7) * (1.0f / 64.0f), &sn, &cs);
    float2 T1 = make_float2(cs, sn);
    tw.s1[0] = make_float2(1.0f, 0.0f);
#pragma unroll
    for (int m = 1; m < 8; ++m) tw.s1[m] = cmul(tw.s1[m - 1], T1);
    sincosf(-2.0f * PI_F * (float)t * (1.0f / 512.0f), &sn, &cs);
    float2 T2 = make_float2(cs, sn);
    tw.s2[0] = make_float2(1.0f, 0.0f);
#pragma unroll
    for (int m = 1; m < 8; ++m) tw.s2[m] = cmul(tw.s2[m - 1], T2);
}

// 512-pt Stockham radix-8, one wave. In: r[m] = x[t+64m]. Out: r[k] = X[t+64k].
template <int S>
__device__ __forceinline__ void fft512(float2 r[8], const Twid& tw,
                                       float2* b0, float2* b1, int t) {
    bfly8<S>(r);
#pragma unroll
    for (int k = 0; k < 8; ++k) b0[padi(8 * t + k)] = r[k];
    __syncthreads();
#pragma unroll
    for (int m = 0; m < 8; ++m) r[m] = b0[padi(t + 64 * m)];
#pragma unroll
    for (int m = 1; m < 8; ++m) r[m] = cmul_tw<S>(r[m], tw.s1[m]);
    bfly8<S>(r);
    int base = ((t >> 3) << 6) + (t & 7);
#pragma unroll
    for (int k = 0; k < 8; ++k) b1[padi(base + 8 * k)] = r[k];
    __syncthreads();
#pragma unroll
    for (int m = 0; m < 8; ++m) r[m] = b1[padi(t + 64 * m)];
#pragma unroll
    for (int m = 1; m < 8; ++m) r[m] = cmul_tw<S>(r[m], tw.s2[m]);
    bfly8<S>(r);
}

// stencil: partial for both fields at row i, cols t+64m (bitwise-shared by kA/kC)
__device__ __forceinline__ void stencil_row(const float* __restrict__ X,
                                            const float* __restrict__ F,
                                            int i, int t, float p0r[8], float p1r[8]) {
    const int ip = (i + 1) & 511, im = (i + 511) & 511;
    const float* X0 = X;
    const float* X1 = X + NCELL;
#pragma unroll
    for (int m = 0; m < 8; ++m) {
        int j = t + 64 * m;
        int jp = (j + 1) & 511, jm = (j + 511) & 511;
        float x0c = X0[i * WW + j], x1c = X1[i * WW + j];
        float aip = X0[ip * WW + j], aim = X0[im * WW + j];
        float ajp = X0[i * WW + jp], ajm = X0[i * WW + jm];
        p0r[m] = -(x0c * (aip - aim) * 0.5f + x1c * (ajp - ajm) * 0.5f)
               + NU_C * (aip + aim + ajp + ajm - 4.0f * x0c) + F[i * WW + j];
        float bip = X1[ip * WW + j], bim = X1[im * WW + j];
        float bjp = X1[i * WW + jp], bjm = X1[i * WW + jm];
        p1r[m] = -(x0c * (bip - bim) * 0.5f + x1c * (bjp - bjm) * 0.5f)
               + NU_C * (bip + bim + bjp + bjm - 4.0f * x1c) + F[NCELL + i * WW + j];
    }
}

__device__ __forceinline__ float beta_of(float qs) {
    float rN;              // r^1000 = |r|^1000, r = 1-qs
    if (qs < 1.0f)      rN = expf(1000.0f * log1pf(-qs));
    else if (qs > 1.0f) rN = expf(1000.0f * logf(qs - 1.0f));
    else                rN = 0.0f;
    float M = rN - (1.0f - rN) / (4.0f * qs);
    return -10.0f * M * (1.0f / (512.0f * 512.0f));
}

// --------------------------------------------- phase A: stencil + row FFT
__global__ __launch_bounds__(64) void kA(const float* __restrict__ X,
                                         const float* __restrict__ F,
                                         float2* __restrict__ Zt) {
    __shared__ float2 b0[PADDED], b1[PADDED];
    const int b = blockIdx.x, t = threadIdx.x;
    const int i = (b & 7) * 64 + (b >> 3);    // XCD x owns rows [64x,64x+64)
    Twid tw; make_tw(tw, t);
    float p0r[8], p1r[8];
    stencil_row(X, F, i, t, p0r, p1r);
    float2 r[8];
#pragma unroll
    for (int m = 0; m < 8; ++m) r[m] = make_float2(p0r[m], p1r[m]);
    fft512<-1>(r, tw, b0, b1, t);
    // ROW-major coalesced spectrum store (transpose deferred to kB's gather)
#pragma unroll
    for (int k = 0; k < 8; ++k) Zt[i * 512 + t + 64 * k] = r[k];
}

// ------- phase B: mirror-pair col FFT + multiplier + inverse col FFT
// base col c0=(b&7)*32+(b>>3): XCD x owns cols [32x,32x+32) + mirror span.
__global__ __launch_bounds__(128) void kB(const float2* __restrict__ Zt,
                                          float2* __restrict__ W1) {
    __shared__ float2 b0[2][PADDED], b1[2][PADDED];
    const int b = blockIdx.x;
    const int w = threadIdx.x >> 6, t = threadIdx.x & 63;
    const int c0 = (b & 7) * 32 + (b >> 3);   // 0..255, all distinct
    const int cw = (c0 == 0) ? (w ? 256 : 0) : (w ? 512 - c0 : c0);
    const int mw = (c0 == 0) ? w : (w ^ 1);
    float2 r[8];
    // gather column cw from row-major Zt (16-col cacheline groups XCD-local)
#pragma unroll
    for (int m = 0; m < 8; ++m) r[m] = Zt[(t + 64 * m) * 512 + cw];

    // ---- precompute (in the gather shadow): twiddles + ALL multiplier
    // constants, incl. the log/exp beta chain (index-only, off critical path)
    Twid tw; make_tw(tw, t);
    float shy, chy;
    sincosf(PI_F * (float)cw * (1.0f / 512.0f), &shy, &chy);
    const float sy = 2.0f * shy * chy;   // sin(2 pi cw/512)
    const float qy = shy * shy;          // sin^2(pi cw/512)
    float sxk[8], betak[8];
    {
        float sh, ch;
        sincosf(PI_F * (float)t * (1.0f / 512.0f), &sh, &ch);
        const float c8 = 0.92387953251128675613f;  // cos(pi/8)
        const float s8 = 0.38268343236508977173f;  // sin(pi/8)
#pragma unroll
        for (int k = 0; k < 8; ++k) {
            int ki = t + 64 * k;
            sxk[k] = 2.0f * sh * ch;
            float qs = sh * sh + qy;
            betak[k] = (ki == 0 && cw == 0) ? 0.0f : beta_of(qs);
            float nch = ch * c8 - sh * s8;         // advance angle by pi/8
            sh = sh * c8 + ch * s8;
            ch = nch;
        }
    }

    fft512<-1>(r, tw, b0[w], b1[w], t);
    // stage spectrum for mirror access (aliases b0; own-wave region)
#pragma unroll
    for (int k = 0; k < 8; ++k) b0[w][t + 64 * k] = r[k];
    __syncthreads();

    // multiplier: pure mul/add + LDS mirror reads (short inter-FFT path)
#pragma unroll
    for (int k = 0; k < 8; ++k) {
        int ki = t + 64 * k;
        int mi = (HH - ki) & 511;
        float2 z  = r[k];                      // Z(k) (own spectrum, regs)
        float2 zc = b0[mw][mi];                // Z(-k) from mirror wave's LDS
        float sx = sxk[k];
        float su  = sx * sx + sy * sy;
        float u2x = sx * sx - sy * sy;
        float u2y = 2.0f * sx * sy;
        float cx = zc.x, cy = -zc.y;           // conj(Z(-k))
        float tx = u2x * cx - u2y * cy;
        float ty = u2x * cy + u2y * cx;
        float bh = 0.5f * betak[k];
        r[k] = make_float2(bh * (su * z.x + tx), bh * (su * z.y + ty));
    }
    __syncthreads();   // all mirror reads done before inverse FFT clobbers b0
    fft512<1>(r, tw, b0[w], b1[w], t);
    // COLUMN-major coalesced store (transpose deferred to kC's gather)
#pragma unroll
    for (int k = 0; k < 8; ++k) W1[cw * 512 + t + 64 * k] = r[k];
}

// --------------------------------------- phase C: inverse row FFT + output
__global__ __launch_bounds__(64) void kC(const float2* __restrict__ W1,
                                         const float* __restrict__ X,
                                         const float* __restrict__ F,
                                         float* __restrict__ out) {
    __shared__ float2 b0[PADDED], b1[PADDED];
    const int b = blockIdx.x, t = threadIdx.x;
    const int i = (b & 7) * 64 + (b >> 3);    // XCD x owns rows [64x,64x+64)
    Twid tw; make_tw(tw, t);
    float2 r[8];
    // issue row-gather from col-major W1 first (16-row cacheline groups
    // XCD-local); stencil recompute below hides under the gather latency
#pragma unroll
    for (int m = 0; m < 8; ++m) r[m] = W1[(t + 64 * m) * 512 + i];
    float p0r[8], p1r[8];
    stencil_row(X, F, i, t, p0r, p1r);         // bitwise-identical to kA's p
    fft512<1>(r, tw, b0, b1, t);
#pragma unroll
    for (int k = 0; k < 8; ++k) {
        int j = t + 64 * k;
        __builtin_nontemporal_store(p0r[k] - r[k].x, &out[i * WW + j]);
        __builtin_nontemporal_store(p1r[k] - r[k].y, &out[NCELL + i * WW + j]);
    }
}

// ---------------------------------------------------------------------------
extern "C" void kernel_launch(void* const* d_in, const int* in_sizes, int n_in,
                              void* d_out, int out_size, void* d_ws, size_t ws_size,
                              hipStream_t stream) {
    const float* X = (const float*)d_in[1];
    const float* F = (const float*)d_in[2];
    float* out = (float*)d_out;
    float* ws  = (float*)d_ws;

    float2* Zt = (float2*)ws;                 // NCELL float2 (2 MB), row-major
    float2* W1 = Zt + NCELL;                  // NCELL float2 (2 MB), col-major

    kA<<<dim3(512), dim3(64),  0, stream>>>(X, F, Zt);
    kB<<<dim3(256), dim3(128), 0, stream>>>(Zt, W1);
    kC<<<dim3(512), dim3(64),  0, stream>>>(W1, X, F, out);
}

// Round 10
// 72.459 us; speedup vs baseline: 1.0779x; 1.0124x over previous
//
#include <hip/hip_runtime.h>
#include <math.h>

// Spectral NS projection step, 512x512 fp32 periodic — radix-8 register FFT.
//
// v10: v9 + barrier surgery.
//  - fft512's __syncthreads -> __builtin_amdgcn_wave_barrier() (compile-time
//    fence, 0 instructions): the Stockham exchange buffers are WAVE-PRIVATE
//    and CDNA DS ops complete in program order within a wave, so cross-lane
//    LDS exchange needs only a compiler reordering fence. In kB (2 waves)
//    each __syncthreads was a real rendezvous + vmcnt/lgkmcnt(0) drain.
//  - kB: spectrum staged in a SEPARATE zst[2][512] buffer (inverse FFT never
//    touches it) -> the clobber-protection barrier is gone; exactly ONE real
//    __syncthreads remains in the whole pipeline.
//  - kA: stencil loads issued before twiddle gen; kC: gathers issued first.
//
//  kA (512x64) : row i=(b&7)*64+(b>>3); stencil + fwd row FFT; Zt row-major.
//  kB (256x128): base col c0=(b&7)*32+(b>>3); wave w: col {c0, 512-c0}
//                (c0==0 -> {0,256}, self-mirror); gather col from Zt, fwd
//                FFT, conj(Z(-k)) via zst LDS (mirror wave), exact-Jacobi
//                multiplier (beta chain precomputed in gather shadow),
//                inv FFT, W1 col-major.
//  kC (512x64) : row i=(b&7)*64+(b>>3); gather row from W1, inv row FFT,
//                recompute p, out = p - grad(phi) (nontemporal).
//
// Multiplier (exact identity): M = r^1000 - (1-r^1000)/(4-s), r=s/4,
//   s=2cos ai+2cos aj;  4-s = 4(sin^2(ai/2)+sin^2(aj/2)) (cancellation-free)
//   W(k) = (beta/2)[(sx^2+sy^2) Z(k) + (sx+i sy)^2 conj(Z(-k))], beta=-10M/512^2
// sin/cos over k stepped by pi/8 Givens rotation (1 sincosf per thread).
//
// Stockham radix-8, 3 stages, reads always buf[t+64m] (conflict-free);
// LDS scatter writes padded by idx+(idx>>3) -> near-uniform bank usage.

#define HH 512
#define WW 512
#define NCELL (HH * WW)
#define NU_C 0.1f
#define PI_F 3.14159265358979323846f
#define PADDED 576   // pad(511)=574

#define WBAR() __builtin_amdgcn_wave_barrier()

__device__ __forceinline__ int padi(int i) { return i + (i >> 3); }

__device__ __forceinline__ float2 cadd(float2 a, float2 b) { return make_float2(a.x + b.x, a.y + b.y); }
__device__ __forceinline__ float2 csub(float2 a, float2 b) { return make_float2(a.x - b.x, a.y - b.y); }
__device__ __forceinline__ float2 cmul(float2 a, float2 b) {
    return make_float2(a.x * b.x - a.y * b.y, a.x * b.y + a.y * b.x);
}

// twiddle tables are stored FORWARD (cis(-theta)); inverse conjugates on use
template <int S>
__device__ __forceinline__ float2 cmul_tw(float2 a, float2 w) {
    float wy = (S < 0) ? w.y : -w.y;
    return make_float2(a.x * w.x - a.y * wy, a.x * wy + a.y * w.x);
}

// 8-point DFT, S=-1 forward (e^{-2pi i km/8}), S=+1 inverse
template <int S>
__device__ __forceinline__ void bfly8(float2 r[8]) {
    const float c = 0.70710678118654752f;
    const float s = (float)S;
    float2 e0 = cadd(r[0], r[4]), f0 = csub(r[0], r[4]);
    float2 e1 = cadd(r[2], r[6]), f1 = csub(r[2], r[6]);
    float2 g0 = cadd(r[1], r[5]), h0 = csub(r[1], r[5]);
    float2 g1 = cadd(r[3], r[7]), h1 = csub(r[3], r[7]);
    float2 E0 = cadd(e0, e1), E2 = csub(e0, e1);
    float2 if1 = make_float2(-s * f1.y, s * f1.x);       // s*i*f1
    float2 E1 = cadd(f0, if1), E3 = csub(f0, if1);
    float2 O0 = cadd(g0, g1), O2 = csub(g0, g1);
    float2 ih1 = make_float2(-s * h1.y, s * h1.x);
    float2 O1 = cadd(h0, ih1), O3 = csub(h0, ih1);
    float2 t1 = make_float2(c * (O1.x - s * O1.y), c * (O1.y + s * O1.x)); // W8^s1 * O1
    float2 t2 = make_float2(-s * O2.y, s * O2.x);                          // s*i*O2
    float2 t3 = make_float2(-c * (O3.x + s * O3.y), -c * (O3.y - s * O3.x));
    r[0] = cadd(E0, O0); r[4] = csub(E0, O0);
    r[1] = cadd(E1, t1); r[5] = csub(E1, t1);
    r[2] = cadd(E2, t2); r[6] = csub(E2, t2);
    r[3] = cadd(E3, t3); r[7] = csub(E3, t3);
}

struct Twid { float2 s1[8]; float2 s2[8]; };

__device__ __forceinline__ void make_tw(Twid& tw, int t) {
    float sn, cs;
    sincosf(-2.0f * PI_F * (float)(t & 7) * (1.0f / 64.0f), &sn, &cs);
    float2 T1 = make_float2(cs, sn);
    tw.s1[0] = make_float2(1.0f, 0.0f);
#pragma unroll
    for (int m = 1; m < 8; ++m) tw.s1[m] = cmul(tw.s1[m - 1], T1);
    sincosf(-2.0f * PI_F * (float)t * (1.0f / 512.0f), &sn, &cs);
    float2 T2 = make_float2(cs, sn);
    tw.s2[0] = make_float2(1.0f, 0.0f);
#pragma unroll
    for (int m = 1; m < 8; ++m) tw.s2[m] = cmul(tw.s2[m - 1], T2);
}

// 512-pt Stockham radix-8, one wave, wave-private LDS buffers.
// Cross-lane exchange ordering: wave_barrier (compiler fence) + CDNA's
// in-order per-wave DS pipeline; no block barrier needed.
template <int S>
__device__ __forceinline__ void fft512(float2 r[8], const Twid& tw,
                                       float2* b0, float2* b1, int t) {
    bfly8<S>(r);
#pragma unroll
    for (int k = 0; k < 8; ++k) b0[padi(8 * t + k)] = r[k];
    WBAR();
#pragma unroll
    for (int m = 0; m < 8; ++m) r[m] = b0[padi(t + 64 * m)];
#pragma unroll
    for (int m = 1; m < 8; ++m) r[m] = cmul_tw<S>(r[m], tw.s1[m]);
    bfly8<S>(r);
    int base = ((t >> 3) << 6) + (t & 7);
#pragma unroll
    for (int k = 0; k < 8; ++k) b1[padi(base + 8 * k)] = r[k];
    WBAR();
#pragma unroll
    for (int m = 0; m < 8; ++m) r[m] = b1[padi(t + 64 * m)];
#pragma unroll
    for (int m = 1; m < 8; ++m) r[m] = cmul_tw<S>(r[m], tw.s2[m]);
    bfly8<S>(r);
}

// stencil: partial for both fields at row i, cols t+64m (bitwise-shared by kA/kC)
__device__ __forceinline__ void stencil_row(const float* __restrict__ X,
                                            const float* __restrict__ F,
                                            int i, int t, float p0r[8], float p1r[8]) {
    const int ip = (i + 1) & 511, im = (i + 511) & 511;
    const float* X0 = X;
    const float* X1 = X + NCELL;
#pragma unroll
    for (int m = 0; m < 8; ++m) {
        int j = t + 64 * m;
        int jp = (j + 1) & 511, jm = (j + 511) & 511;
        float x0c = X0[i * WW + j], x1c = X1[i * WW + j];
        float aip = X0[ip * WW + j], aim = X0[im * WW + j];
        float ajp = X0[i * WW + jp], ajm = X0[i * WW + jm];
        p0r[m] = -(x0c * (aip - aim) * 0.5f + x1c * (ajp - ajm) * 0.5f)
               + NU_C * (aip + aim + ajp + ajm - 4.0f * x0c) + F[i * WW + j];
        float bip = X1[ip * WW + j], bim = X1[im * WW + j];
        float bjp = X1[i * WW + jp], bjm = X1[i * WW + jm];
        p1r[m] = -(x0c * (bip - bim) * 0.5f + x1c * (bjp - bjm) * 0.5f)
               + NU_C * (bip + bim + bjp + bjm - 4.0f * x1c) + F[NCELL + i * WW + j];
    }
}

__device__ __forceinline__ float beta_of(float qs) {
    float rN;              // r^1000 = |r|^1000, r = 1-qs
    if (qs < 1.0f)      rN = expf(1000.0f * log1pf(-qs));
    else if (qs > 1.0f) rN = expf(1000.0f * logf(qs - 1.0f));
    else                rN = 0.0f;
    float M = rN - (1.0f - rN) / (4.0f * qs);
    return -10.0f * M * (1.0f / (512.0f * 512.0f));
}

// --------------------------------------------- phase A: stencil + row FFT
__global__ __launch_bounds__(64) void kA(const float* __restrict__ X,
                                         const float* __restrict__ F,
                                         float2* __restrict__ Zt) {
    __shared__ float2 b0[PADDED], b1[PADDED];
    const int b = blockIdx.x, t = threadIdx.x;
    const int i = (b & 7) * 64 + (b >> 3);    // XCD x owns rows [64x,64x+64)
    // stencil loads issue first; twiddle gen overlaps their latency
    float p0r[8], p1r[8];
    stencil_row(X, F, i, t, p0r, p1r);
    Twid tw; make_tw(tw, t);
    float2 r[8];
#pragma unroll
    for (int m = 0; m < 8; ++m) r[m] = make_float2(p0r[m], p1r[m]);
    fft512<-1>(r, tw, b0, b1, t);
    // ROW-major coalesced spectrum store (transpose deferred to kB's gather)
#pragma unroll
    for (int k = 0; k < 8; ++k) Zt[i * 512 + t + 64 * k] = r[k];
}

// ------- phase B: mirror-pair col FFT + multiplier + inverse col FFT
// base col c0=(b&7)*32+(b>>3): XCD x owns cols [32x,32x+32) + mirror span.
__global__ __launch_bounds__(128) void kB(const float2* __restrict__ Zt,
                                          float2* __restrict__ W1) {
    __shared__ float2 b0[2][PADDED], b1[2][PADDED];
    __shared__ float2 zst[2][512];            // spectrum stage (mirror access)
    const int b = blockIdx.x;
    const int w = threadIdx.x >> 6, t = threadIdx.x & 63;
    const int c0 = (b & 7) * 32 + (b >> 3);   // 0..255, all distinct
    const int cw = (c0 == 0) ? (w ? 256 : 0) : (w ? 512 - c0 : c0);
    const int mw = (c0 == 0) ? w : (w ^ 1);
    float2 r[8];
    // gather column cw from row-major Zt (16-col cacheline groups XCD-local)
#pragma unroll
    for (int m = 0; m < 8; ++m) r[m] = Zt[(t + 64 * m) * 512 + cw];

    // ---- precompute (in the gather shadow): twiddles + ALL multiplier
    // constants, incl. the log/exp beta chain (index-only, off critical path)
    Twid tw; make_tw(tw, t);
    float shy, chy;
    sincosf(PI_F * (float)cw * (1.0f / 512.0f), &shy, &chy);
    const float sy = 2.0f * shy * chy;   // sin(2 pi cw/512)
    const float qy = shy * shy;          // sin^2(pi cw/512)
    float sxk[8], betak[8];
    {
        float sh, ch;
        sincosf(PI_F * (float)t * (1.0f / 512.0f), &sh, &ch);
        const float c8 = 0.92387953251128675613f;  // cos(pi/8)
        const float s8 = 0.38268343236508977173f;  // sin(pi/8)
#pragma unroll
        for (int k = 0; k < 8; ++k) {
            int ki = t + 64 * k;
            sxk[k] = 2.0f * sh * ch;
            float qs = sh * sh + qy;
            betak[k] = (ki == 0 && cw == 0) ? 0.0f : beta_of(qs);
            float nch = ch * c8 - sh * s8;         // advance angle by pi/8
            sh = sh * c8 + ch * s8;
            ch = nch;
        }
    }

    fft512<-1>(r, tw, b0[w], b1[w], t);
    // stage spectrum in its own buffer (inverse FFT never touches zst)
#pragma unroll
    for (int k = 0; k < 8; ++k) zst[w][t + 64 * k] = r[k];
    __syncthreads();   // the ONLY block barrier: sibling's stage visible

    // multiplier: pure mul/add + LDS mirror reads (short inter-FFT path)
#pragma unroll
    for (int k = 0; k < 8; ++k) {
        int ki = t + 64 * k;
        int mi = (HH - ki) & 511;
        float2 z  = r[k];                      // Z(k) (own spectrum, regs)
        float2 zc = zst[mw][mi];               // Z(-k) from mirror wave's stage
        float sx = sxk[k];
        float su  = sx * sx + sy * sy;
        float u2x = sx * sx - sy * sy;
        float u2y = 2.0f * sx * sy;
        float cx = zc.x, cy = -zc.y;           // conj(Z(-k))
        float tx = u2x * cx - u2y * cy;
        float ty = u2x * cy + u2y * cx;
        float bh = 0.5f * betak[k];
        r[k] = make_float2(bh * (su * z.x + tx), bh * (su * z.y + ty));
    }
    // no second barrier: inv FFT uses only wave-private b0[w]/b1[w]
    fft512<1>(r, tw, b0[w], b1[w], t);
    // COLUMN-major coalesced store (transpose deferred to kC's gather)
#pragma unroll
    for (int k = 0; k < 8; ++k) W1[cw * 512 + t + 64 * k] = r[k];
}

// --------------------------------------- phase C: inverse row FFT + output
__global__ __launch_bounds__(64) void kC(const float2* __restrict__ W1,
                                         const float* __restrict__ X,
                                         const float* __restrict__ F,
                                         float* __restrict__ out) {
    __shared__ float2 b0[PADDED], b1[PADDED];
    const int b = blockIdx.x, t = threadIdx.x;
    const int i = (b & 7) * 64 + (b >> 3);    // XCD x owns rows [64x,64x+64)
    float2 r[8];
    // row-gather from col-major W1 issued first (16-row cacheline groups
    // XCD-local); twiddle gen + stencil recompute hide under gather latency
#pragma unroll
    for (int m = 0; m < 8; ++m) r[m] = W1[(t + 64 * m) * 512 + i];
    Twid tw; make_tw(tw, t);
    float p0r[8], p1r[8];
    stencil_row(X, F, i, t, p0r, p1r);         // bitwise-identical to kA's p
    fft512<1>(r, tw, b0, b1, t);
#pragma unroll
    for (int k = 0; k < 8; ++k) {
        int j = t + 64 * k;
        __builtin_nontemporal_store(p0r[k] - r[k].x, &out[i * WW + j]);
        __builtin_nontemporal_store(p1r[k] - r[k].y, &out[NCELL + i * WW + j]);
    }
}

// ---------------------------------------------------------------------------
extern "C" void kernel_launch(void* const* d_in, const int* in_sizes, int n_in,
                              void* d_out, int out_size, void* d_ws, size_t ws_size,
                              hipStream_t stream) {
    const float* X = (const float*)d_in[1];
    const float* F = (const float*)d_in[2];
    float* out = (float*)d_out;
    float* ws  = (float*)d_ws;

    float2* Zt = (float2*)ws;                 // NCELL float2 (2 MB), row-major
    float2* W1 = Zt + NCELL;                  // NCELL float2 (2 MB), col-major

    kA<<<dim3(512), dim3(64),  0, stream>>>(X, F, Zt);
    kB<<<dim3(256), dim3(128), 0, stream>>>(Zt, W1);
    kC<<<dim3(512), dim3(64),  0, stream>>>(W1, X, F, out);
}